// Round 1
// baseline (125.613 us; speedup 1.0000x reference)
//
#include <hip/hip_runtime.h>
#include <math.h>

// ClipStyleContrastiveLoss on MI355X.
// S1[i] = rowsum(exp(L/t))[i] + colsum(exp(L/t))[i] - 2*exp(L[i,i]/t)
// S2[i] = same with exp(2L/t) = e^2
// loss[i] = log((pos + Ng + eps)/pos), answer = mean over B rows (2B rows are duplicated pairs).

#define THREADS    256
#define TILE_ROWS  16
// 1/(TEMPERATURE * ln2) = 2/ln(2): exp(x/t) = exp2(x * EXP_SCALE)
#define EXP_SCALE  2.885390081777927f

__global__ __launch_bounds__(THREADS) void sums_kernel(
    const float* __restrict__ L,
    float* __restrict__ sumE,
    float* __restrict__ sumE2,
    int B)
{
    // Block tile: TILE_ROWS rows x 1024 cols. Thread owns 4 contiguous cols.
    __shared__ float2 rp[TILE_ROWS][THREADS];   // per-thread row partials (E, E2) — 32 KB

    const int t       = threadIdx.x;
    const int colBase = blockIdx.x * (THREADS * 4) + 4 * t;
    const int row0    = blockIdx.y * TILE_ROWS;

    float c0 = 0.f, c1 = 0.f, c2 = 0.f, c3 = 0.f;      // col partials of E
    float d0 = 0.f, d1 = 0.f, d2 = 0.f, d3 = 0.f;      // col partials of E^2

#pragma unroll
    for (int r = 0; r < TILE_ROWS; ++r) {
        const float4 x = *reinterpret_cast<const float4*>(
            L + (size_t)(row0 + r) * B + colBase);
        float e0 = exp2f(x.x * EXP_SCALE);
        float e1 = exp2f(x.y * EXP_SCALE);
        float e2 = exp2f(x.z * EXP_SCALE);
        float e3 = exp2f(x.w * EXP_SCALE);
        float q0 = e0 * e0, q1 = e1 * e1, q2 = e2 * e2, q3 = e3 * e3;
        c0 += e0; c1 += e1; c2 += e2; c3 += e3;
        d0 += q0; d1 += q1; d2 += q2; d3 += q3;
        rp[r][t] = make_float2((e0 + e1) + (e2 + e3), (q0 + q1) + (q2 + q3));
    }
    __syncthreads();

    // Row reduction: wave w handles rows w, w+4, w+8, w+12.
    const int wave = t >> 6;
    const int lane = t & 63;
#pragma unroll
    for (int r = wave; r < TILE_ROWS; r += 4) {
        float2 a = rp[r][lane];
        float2 b = rp[r][lane + 64];
        float2 c = rp[r][lane + 128];
        float2 d = rp[r][lane + 192];
        float se  = (a.x + b.x) + (c.x + d.x);
        float se2 = (a.y + b.y) + (c.y + d.y);
#pragma unroll
        for (int off = 32; off > 0; off >>= 1) {
            se  += __shfl_down(se,  off, 64);
            se2 += __shfl_down(se2, off, 64);
        }
        if (lane == 0) {
            atomicAdd(&sumE [row0 + r], se);
            atomicAdd(&sumE2[row0 + r], se2);
        }
    }

    // Column partials: unique addresses per thread within the block.
    atomicAdd(&sumE [colBase + 0], c0);
    atomicAdd(&sumE [colBase + 1], c1);
    atomicAdd(&sumE [colBase + 2], c2);
    atomicAdd(&sumE [colBase + 3], c3);
    atomicAdd(&sumE2[colBase + 0], d0);
    atomicAdd(&sumE2[colBase + 1], d1);
    atomicAdd(&sumE2[colBase + 2], d2);
    atomicAdd(&sumE2[colBase + 3], d3);
}

__global__ __launch_bounds__(THREADS) void finalize_kernel(
    const float* __restrict__ L,
    const float* __restrict__ sumE,
    const float* __restrict__ sumE2,
    float* __restrict__ out,
    int B)
{
    const int t = threadIdx.x;
    const float Nf = (float)(2 * B - 2);
    float acc = 0.f;

    for (int i = t; i < B; i += THREADS) {
        float dg  = L[(size_t)i * B + i];
        float pe  = exp2f(dg * EXP_SCALE);
        float S1  = sumE [i] - 2.f * pe;
        float S2  = sumE2[i] - 2.f * (pe * pe);
        float rw  = Nf * (S2 / S1);                       // N * sum(neg^2)/sum(neg)
        float Ng  = (rw - 0.1f * Nf * pe) * (1.f / 0.9f); // (-tau*N*pos + rw)/(1-tau)
        float fl  = Nf * 0.13533528323661270f;            // N * exp(-1/t) = N * e^-2
        Ng = fmaxf(Ng, fl);
        acc += logf((pe + Ng + 1e-8f) / pe);              // -log(pos/(pos+Ng+eps))
    }

    // wave reduce then cross-wave via LDS
#pragma unroll
    for (int off = 32; off > 0; off >>= 1) acc += __shfl_down(acc, off, 64);
    __shared__ float wsum[4];
    const int wave = t >> 6;
    const int lane = t & 63;
    if (lane == 0) wsum[wave] = acc;
    __syncthreads();
    if (t == 0) out[0] = (wsum[0] + wsum[1] + wsum[2] + wsum[3]) / (float)B;
}

extern "C" void kernel_launch(void* const* d_in, const int* in_sizes, int n_in,
                              void* d_out, int out_size, void* d_ws, size_t ws_size,
                              hipStream_t stream) {
    const float* L = (const float*)d_in[0];
    // B*B elements
    int B = 1;
    while ((long long)B * B < (long long)in_sizes[0]) B <<= 1;  // B = 4096 for 16.7M

    float* sumE  = (float*)d_ws;
    float* sumE2 = sumE + B;

    hipMemsetAsync(d_ws, 0, (size_t)2 * B * sizeof(float), stream);

    dim3 grid(B / (THREADS * 4), B / TILE_ROWS);   // (4, 256) for B=4096
    sums_kernel<<<grid, THREADS, 0, stream>>>(L, sumE, sumE2, B);
    finalize_kernel<<<1, THREADS, 0, stream>>>(L, sumE, sumE2, (float*)d_out, B);
}

// Round 2
// 103.285 us; speedup vs baseline: 1.2162x; 1.2162x over previous
//
#include <hip/hip_runtime.h>
#include <math.h>

// ClipStyleContrastiveLoss on MI355X (gfx950).
// Math reduction (BETA=1 => imp==neg):
//   E = exp(L/t), with exp(2L/t) = E^2
//   S1[i] = rowsum(E)[i] + colsum(E)[i] - 2*E[i,i]
//   S2[i] = rowsum(E^2)[i] + colsum(E^2)[i] - 2*E[i,i]^2
//   reweight = N * S2/S1 ; Ng = (reweight - tau*N*pos)/(1-tau), clamped
//   loss = mean over B rows of log((pos+Ng+eps)/pos)   (2B rows are duplicate pairs)
//
// R2: column atomics (2M EA RMWs, the R1 bottleneck: WRITE_SIZE 33.8MB = 2.1M x 16B)
// replaced by per-stripe partial stores (8MB ws) + parallel merge pass.

#define THREADS    256
#define TILE_ROWS  16
// 1/(TEMPERATURE * ln2) = 2/ln(2): exp(x/t) = exp2(x * EXP_SCALE)
#define EXP_SCALE  2.885390081777927f

__global__ __launch_bounds__(THREADS) void pass1_kernel(
    const float* __restrict__ L,
    float* __restrict__ rowE,     // [B]  atomic-accumulated row sums of E
    float* __restrict__ rowE2,    // [B]  atomic-accumulated row sums of E^2
    float* __restrict__ colPE,    // [S][B] per-stripe column partials of E
    float* __restrict__ colPE2,   // [S][B] per-stripe column partials of E^2
    int B)
{
    __shared__ float2 rp[TILE_ROWS][THREADS];   // per-thread row partials — 32 KB

    const int t       = threadIdx.x;
    const int colBase = blockIdx.x * (THREADS * 4) + 4 * t;
    const int s       = blockIdx.y;             // row stripe index
    const int row0    = s * TILE_ROWS;

    float c0 = 0.f, c1 = 0.f, c2 = 0.f, c3 = 0.f;   // col partials of E
    float d0 = 0.f, d1 = 0.f, d2 = 0.f, d3 = 0.f;   // col partials of E^2

#pragma unroll
    for (int r = 0; r < TILE_ROWS; ++r) {
        const float4 x = *reinterpret_cast<const float4*>(
            L + (size_t)(row0 + r) * B + colBase);
        float e0 = exp2f(x.x * EXP_SCALE);
        float e1 = exp2f(x.y * EXP_SCALE);
        float e2 = exp2f(x.z * EXP_SCALE);
        float e3 = exp2f(x.w * EXP_SCALE);
        float q0 = e0 * e0, q1 = e1 * e1, q2 = e2 * e2, q3 = e3 * e3;
        c0 += e0; c1 += e1; c2 += e2; c3 += e3;
        d0 += q0; d1 += q1; d2 += q2; d3 += q3;
        rp[r][t] = make_float2((e0 + e1) + (e2 + e3), (q0 + q1) + (q2 + q3));
    }
    __syncthreads();

    // Row reduction: wave w handles rows w, w+4, w+8, w+12. 32 atomics/block total.
    const int wave = t >> 6;
    const int lane = t & 63;
#pragma unroll
    for (int r = wave; r < TILE_ROWS; r += 4) {
        float2 a = rp[r][lane];
        float2 b = rp[r][lane + 64];
        float2 c = rp[r][lane + 128];
        float2 d = rp[r][lane + 192];
        float se  = (a.x + b.x) + (c.x + d.x);
        float se2 = (a.y + b.y) + (c.y + d.y);
#pragma unroll
        for (int off = 32; off > 0; off >>= 1) {
            se  += __shfl_down(se,  off, 64);
            se2 += __shfl_down(se2, off, 64);
        }
        if (lane == 0) {
            atomicAdd(&rowE [row0 + r], se);
            atomicAdd(&rowE2[row0 + r], se2);
        }
    }

    // Column partials: plain coalesced float4 stores, no conflicts.
    *reinterpret_cast<float4*>(colPE  + (size_t)s * B + colBase) = make_float4(c0, c1, c2, c3);
    *reinterpret_cast<float4*>(colPE2 + (size_t)s * B + colBase) = make_float4(d0, d1, d2, d3);
}

// Merge stripe col-partials + row sums + diag -> loss; one atomic per block.
// Block b handles indices i in [16b, 16b+16).
__global__ __launch_bounds__(THREADS) void pass2_kernel(
    const float* __restrict__ L,
    const float* __restrict__ rowE,
    const float* __restrict__ rowE2,
    const float* __restrict__ colPE,
    const float* __restrict__ colPE2,
    float* __restrict__ out,
    int B, int S)
{
    const int t    = threadIdx.x;
    const int c    = t & 15;     // col within the block's 16-col range
    const int g    = t >> 4;     // stripe group, 16 groups
    const int base = blockIdx.x * 16;

    float se = 0.f, se2 = 0.f;
    for (int k = g; k < S; k += 16) {
        se  += colPE [(size_t)k * B + base + c];
        se2 += colPE2[(size_t)k * B + base + c];
    }
    __shared__ float2 part[16][17];
    part[g][c] = make_float2(se, se2);
    __syncthreads();

    if (t < 16) {
        float colE = 0.f, colE2 = 0.f;
#pragma unroll
        for (int gg = 0; gg < 16; ++gg) {
            colE  += part[gg][t].x;
            colE2 += part[gg][t].y;
        }
        const int i  = base + t;
        const float Nf = (float)(2 * B - 2);
        float dg = L[(size_t)i * B + i];
        float pe = exp2f(dg * EXP_SCALE);
        float S1 = rowE [i] + colE  - 2.f * pe;
        float S2 = rowE2[i] + colE2 - 2.f * (pe * pe);
        float rw = Nf * (S2 / S1);                        // N * sum(neg^2)/sum(neg)
        float Ng = (rw - 0.1f * Nf * pe) * (1.f / 0.9f);  // (-tau*N*pos + rw)/(1-tau)
        Ng = fmaxf(Ng, Nf * 0.13533528323661270f);        // N * e^{-1/t}
        float loss = logf((pe + Ng + 1e-8f) / pe);
        // reduce lanes 0..15 of wave 0
#pragma unroll
        for (int off = 8; off > 0; off >>= 1) loss += __shfl_down(loss, off, 16);
        if (t == 0) atomicAdd(out, loss / (float)B);
    }
}

extern "C" void kernel_launch(void* const* d_in, const int* in_sizes, int n_in,
                              void* d_out, int out_size, void* d_ws, size_t ws_size,
                              hipStream_t stream) {
    const float* L = (const float*)d_in[0];
    int B = 1;
    while ((long long)B * B < (long long)in_sizes[0]) B <<= 1;  // B = 4096
    const int S = B / TILE_ROWS;                                // 256 stripes

    float* rowE   = (float*)d_ws;
    float* rowE2  = rowE  + B;
    float* colPE  = rowE2 + B;
    float* colPE2 = colPE + (size_t)S * B;
    // ws bytes needed: (2B + 2*S*B)*4 = 8.4 MB for B=4096

    hipMemsetAsync(d_ws, 0, (size_t)2 * B * sizeof(float), stream);  // rowE/rowE2
    hipMemsetAsync(d_out, 0, sizeof(float), stream);

    dim3 grid1(B / (THREADS * 4), B / TILE_ROWS);   // (4, 256)
    pass1_kernel<<<grid1, THREADS, 0, stream>>>(L, rowE, rowE2, colPE, colPE2, B);
    pass2_kernel<<<B / 16, THREADS, 0, stream>>>(L, rowE, rowE2, colPE, colPE2,
                                                 (float*)d_out, B, S);
}